// Round 7
// baseline (289.251 us; speedup 1.0000x reference)
//
#include <hip/hip_runtime.h>
#include <math.h>

constexpr int B = 4;
constexpr int N = 8192;
constexpr int KNN = 8;
constexpr int NCELL = 4096;              // 16^3 Morton cells
constexpr int GSIZE = 16;                // points per group
constexpr int NGRP = N / GSIZE;          // 512 groups per cloud-batch
constexpr int NSUP = 64;                 // supers: 8 groups (128 pts)
constexpr int NCB = 2 * B;               // cloud-batches (0-3 pred, 4-7 tgt)

// Insert tv into sorted ascending d[0..7]. Exact: d'[0]=min(d0,tv),
// d'[i]=med3(d[i-1],d[i],tv). 8 independent ops. INF insert is a no-op.
__device__ __forceinline__ void insert8(float (&d)[KNN], float tv) {
  float n0 = fminf(d[0], tv);
  float n1 = __builtin_amdgcn_fmed3f(d[0], d[1], tv);
  float n2 = __builtin_amdgcn_fmed3f(d[1], d[2], tv);
  float n3 = __builtin_amdgcn_fmed3f(d[2], d[3], tv);
  float n4 = __builtin_amdgcn_fmed3f(d[3], d[4], tv);
  float n5 = __builtin_amdgcn_fmed3f(d[4], d[5], tv);
  float n6 = __builtin_amdgcn_fmed3f(d[5], d[6], tv);
  float n7 = __builtin_amdgcn_fmed3f(d[6], d[7], tv);
  d[0] = n0; d[1] = n1; d[2] = n2; d[3] = n3;
  d[4] = n4; d[5] = n5; d[6] = n6; d[7] = n7;
}

__device__ __forceinline__ int morton3(int x, int y, int z) {
  int m = 0;
#pragma unroll
  for (int b = 0; b < 4; ++b)
    m |= (((x >> b) & 1) << (3 * b + 2)) | (((y >> b) & 1) << (3 * b + 1)) |
         (((z >> b) & 1) << (3 * b + 0));
  return m;
}

__device__ __forceinline__ int point_cell(float x, float y, float z) {
  int cx = (int)fminf(fmaxf((x + 4.0f) * 2.0f, 0.0f), 15.0f);
  int cy = (int)fminf(fmaxf((y + 4.0f) * 2.0f, 0.0f), 15.0f);
  int cz = (int)fminf(fmaxf((z + 4.0f) * 2.0f, 0.0f), 15.0f);
  return morton3(cx, cy, cz);
}

// One block per cloud-batch (8 blocks x 1024 threads). LDS histogram ->
// in-block scan (global starts) -> scatter (points in registers) ->
// group/super AABBs. Verified structure (absmax 0 since round 4).
__global__ __launch_bounds__(1024) void prep_kernel(
    const float* __restrict__ src, const float* __restrict__ tgt,
    const float* __restrict__ flow, float4* __restrict__ pred_s,
    float4* __restrict__ tgt_s, int* __restrict__ starts,
    float4* __restrict__ gbox, float4* __restrict__ sbox,
    float* __restrict__ out) {
  __shared__ int hist[NCELL];              // 16 KB: counts -> cursor
  __shared__ int wsum[16];
  __shared__ float4 gcache[2 * NGRP];      // 16 KB
  int tid = threadIdx.x, cb = blockIdx.x;
  int cloud = cb >> 2, batch = cb & 3;
  if (cb == 0 && tid == 0) out[0] = 0.0f;

  for (int i = tid; i < NCELL; i += 1024) hist[i] = 0;
  __syncthreads();

  const float* __restrict__ bp = (cloud == 0 ? src : tgt) + batch * N * 3;
  const float* __restrict__ bf = flow + batch * N * 3;
  float4 pt[8];
  int cell[8];
#pragma unroll
  for (int k = 0; k < 8; ++k) {
    int i = k * 1024 + tid;
    float x = bp[3 * i + 0], y = bp[3 * i + 1], z = bp[3 * i + 2];
    if (cloud == 0) { x += bf[3 * i + 0]; y += bf[3 * i + 1]; z += bf[3 * i + 2]; }
    pt[k] = make_float4(x, y, z, 0.5f * (x * x + y * y + z * z));
    cell[k] = point_cell(x, y, z);
    atomicAdd(&hist[cell[k]], 1);
  }
  __syncthreads();

  int b4 = tid * 4;
  int h0v = hist[b4 + 0], h1v = hist[b4 + 1];
  int h2v = hist[b4 + 2], h3v = hist[b4 + 3];
  int s = h0v + h1v + h2v + h3v;
  int lane = tid & 63, w = tid >> 6;
  int incl = s;
#pragma unroll
  for (int off = 1; off < 64; off <<= 1) {
    int u = __shfl_up(incl, off, 64);
    if (lane >= off) incl += u;
  }
  if (lane == 63) wsum[w] = incl;
  __syncthreads();
  if (tid < 16) {
    int v = wsum[tid], inc = v;
#pragma unroll
    for (int off = 1; off < 16; off <<= 1) {
      int u = __shfl_up(inc, off, 64);
      if (tid >= off) inc += u;
    }
    wsum[tid] = inc - v;
  }
  __syncthreads();
  int run = incl - s + wsum[w];
  int* __restrict__ stg = starts + cb * (NCELL + 1);
  stg[b4 + 0] = run; hist[b4 + 0] = run; run += h0v;
  stg[b4 + 1] = run; hist[b4 + 1] = run; run += h1v;
  stg[b4 + 2] = run; hist[b4 + 2] = run; run += h2v;
  stg[b4 + 3] = run; hist[b4 + 3] = run; run += h3v;
  if (tid == 0) stg[NCELL] = N;
  __syncthreads();

  float4* __restrict__ dst = (cloud == 0 ? pred_s : tgt_s) + batch * N;
#pragma unroll
  for (int k = 0; k < 8; ++k) {
    int pos = atomicAdd(&hist[cell[k]], 1);
    dst[pos] = pt[k];
  }
  __threadfence_block();
  __syncthreads();

  if (tid < NGRP) {
    const float4* __restrict__ sp = dst + tid * GSIZE;
    float lx = INFINITY, ly = INFINITY, lz = INFINITY;
    float hx = -INFINITY, hy = -INFINITY, hz = -INFINITY;
#pragma unroll
    for (int t = 0; t < GSIZE; ++t) {
      float4 p = sp[t];
      lx = fminf(lx, p.x); ly = fminf(ly, p.y); lz = fminf(lz, p.z);
      hx = fmaxf(hx, p.x); hy = fmaxf(hy, p.y); hz = fmaxf(hz, p.z);
    }
    float4 lo = make_float4(lx, ly, lz, 0.0f);
    float4 hi = make_float4(hx, hy, hz, 0.0f);
    gcache[2 * tid] = lo; gcache[2 * tid + 1] = hi;
    gbox[cb * 2 * NGRP + 2 * tid + 0] = lo;
    gbox[cb * 2 * NGRP + 2 * tid + 1] = hi;
  }
  __syncthreads();
  if (tid < NSUP) {
    float lx = INFINITY, ly = INFINITY, lz = INFINITY;
    float hx = -INFINITY, hy = -INFINITY, hz = -INFINITY;
#pragma unroll
    for (int t = 0; t < 8; ++t) {
      float4 lo = gcache[2 * (tid * 8 + t)], hi = gcache[2 * (tid * 8 + t) + 1];
      lx = fminf(lx, lo.x); ly = fminf(ly, lo.y); lz = fminf(lz, lo.z);
      hx = fmaxf(hx, hi.x); hy = fmaxf(hy, hi.y); hz = fmaxf(hz, hi.z);
    }
    sbox[cb * 2 * NSUP + 2 * tid + 0] = make_float4(lx, ly, lz, 0.0f);
    sbox[cb * 2 * NSUP + 2 * tid + 1] = make_float4(hx, hy, hz, 0.0f);
  }
}

// One query per 16-lane SEGMENT (4 queries/wave, lockstep). Candidates are
// the lane dimension: seeds and drained groups are read with coalesced
// per-segment loads; each lane keeps an exact top-8 of the candidates it saw.
// Threshold: seed bound M = max over 8 lane-pairs of pair-min (8 distinct
// candidates <= M => d8(seeds) <= M => final d8 <= M). Supers then groups
// tested vs thr (fixed): every skipped candidate has dist^2 >= boxmin >= thr
// >= final d8 => exact (1e-5 margins cover fp). Selection of the next
// passing super/group is a 4-shfl segment-min over bit-encoded ids (the
// encoding IS the id). Extract: 8 rounds of segment-min + single-owner pop --
// exact selection sort of the union of per-lane top-8 lists, which contains
// the true top-8 (a lane holds at most 8 of them, and keeps its best 8).
__global__ __launch_bounds__(256, 8) void chamfer_kernel(
    const float4* __restrict__ pred_s, const float4* __restrict__ tgt_s,
    const int* __restrict__ starts, const float4* __restrict__ gbox,
    const float4* __restrict__ sbox, float* __restrict__ out) {
  __shared__ float bsum[4];
  int tid = threadIdx.x;
  int lane = tid & 63;
  int sl = lane & 15;                      // lane within segment
  int seg = lane >> 4;                     // segment within wave
  int wv = tid >> 6;
  int gq = blockIdx.x * 16 + wv * 4 + seg; // one query per segment
  int qcb = gq >> 13, idx = gq & (N - 1);
  int ccb = qcb ^ 4;                       // opposite cloud, same batch
  const float4* __restrict__ qarr = (qcb < 4 ? pred_s : tgt_s) + (qcb & 3) * N;
  const float4* __restrict__ parr = (ccb < 4 ? pred_s : tgt_s) + (ccb & 3) * N;
  const int* __restrict__ st = starts + ccb * (NCELL + 1);
  const float4* __restrict__ gb = gbox + ccb * (2 * NGRP);
  const float4* __restrict__ sb = sbox + ccb * (2 * NSUP);

  float4 q = qarr[idx];
  float nqx = -q.x, nqy = -q.y, nqz = -q.z, twoqw = 2.0f * q.w;
  float d[KNN];
#pragma unroll
  for (int i = 0; i < KNN; ++i) d[i] = INFINITY;

  auto boxmd = [&](const float4* __restrict__ bx) {
    float4 lo = bx[0], hi = bx[1];
    float ax = fmaxf(fmaxf(lo.x - q.x, q.x - hi.x), 0.0f);
    float ay = fmaxf(fmaxf(lo.y - q.y, q.y - hi.y), 0.0f);
    float az = fmaxf(fmaxf(lo.z - q.z, q.z - hi.z), 0.0f);
    return __builtin_fmaf(ax, ax, __builtin_fmaf(ay, ay, az * az));
  };
  auto dist = [&](float4 p) {
    return __builtin_fmaf(nqx, p.x, __builtin_fmaf(nqy, p.y,
           __builtin_fmaf(nqz, p.z, p.w)));
  };

  // Seed: the rank-matched super's 128 points, 8 coalesced rounds.
  int ge = st[point_cell(q.x, q.y, q.z)];
  int s0 = min(ge >> 7, NSUP - 1);
  const float4* __restrict__ sp = parr + s0 * 128;
#pragma unroll
  for (int r = 0; r < 8; ++r) insert8(d, dist(sp[r * 16 + sl]));

  // Seed threshold: pair-min (8 distinct winners), max over the 8 pairs.
  float mn = fminf(d[0], __shfl_xor(d[0], 1, 64));
  float mx = fmaxf(mn, __shfl_xor(mn, 2, 64));
  mx = fmaxf(mx, __shfl_xor(mx, 4, 64));
  mx = fmaxf(mx, __shfl_xor(mx, 8, 64));
  float thr = __builtin_fmaf(2.0f, mx, twoqw) * 1.00001f + 1e-5f;

  // Super tests: 4 per lane (super id s = sl + 16*j; encoding (j<<4)|sl = s).
  unsigned smask = 0;
#pragma unroll
  for (int j = 0; j < 4; ++j) {
    int s = sl + 16 * j;
    if (s != s0 && boxmd(sb + 2 * s) < thr) smask |= 1u << j;
  }

  // Descend passing supers -> per-lane group mask pm
  // (group g owned by lane g&15, bit g>>4; encoding (i<<4)|sl = g).
  unsigned pm = 0;
  while (__ballot(smask != 0u)) {
    int mypri = smask ? ((__builtin_ctz(smask) << 4) | sl) : 4096;
    int ss = mypri;
    ss = min(ss, __shfl_xor(ss, 1, 64));
    ss = min(ss, __shfl_xor(ss, 2, 64));
    ss = min(ss, __shfl_xor(ss, 4, 64));
    ss = min(ss, __shfl_xor(ss, 8, 64));   // segment-min = next super id
    if (mypri == ss) smask &= smask - 1;   // unique owner (sl embedded)
    if (ss < 4096) {
      // 8 lanes of matching half test this super's 8 groups.
      if (((sl >> 3) & 1) == (ss & 1)) {
        int g = ss * 8 + (sl & 7);
        if (boxmd(gb + 2 * g) < thr) pm |= 1u << (g >> 4);
      }
    }
  }

  // Drain: one group per segment per round; 16 lanes load its 16 points.
  while (__ballot(pm != 0u)) {
    int mypri = pm ? ((__builtin_ctz(pm) << 4) | sl) : 4096;
    int gg = mypri;
    gg = min(gg, __shfl_xor(gg, 1, 64));
    gg = min(gg, __shfl_xor(gg, 2, 64));
    gg = min(gg, __shfl_xor(gg, 4, 64));
    gg = min(gg, __shfl_xor(gg, 8, 64));   // segment-min = next group id
    if (mypri == gg) pm &= pm - 1;
    float tv = INFINITY;
    if (gg < 4096) tv = dist(parr[gg * 16 + sl]);  // coalesced 256B/segment
    insert8(d, tv);
  }

  // Extract the 8 smallest across the segment (exact selection sort).
  unsigned long long segm = 0xFFFFull << (seg * 16);
  float ssum = 0.0f;
#pragma unroll
  for (int k = 0; k < KNN; ++k) {
    float v = d[0];
    v = fminf(v, __shfl_xor(v, 1, 64));
    v = fminf(v, __shfl_xor(v, 2, 64));
    v = fminf(v, __shfl_xor(v, 4, 64));
    v = fminf(v, __shfl_xor(v, 8, 64));
    unsigned long long bset = __ballot(d[0] == v) & segm;
    if (lane == (int)__builtin_ctzll(bset)) {   // lowest owner pops one copy
      d[0] = d[1]; d[1] = d[2]; d[2] = d[3]; d[3] = d[4];
      d[4] = d[5]; d[5] = d[6]; d[6] = d[7]; d[7] = INFINITY;
    }
    ssum += sqrtf(fmaxf(__builtin_fmaf(2.0f, v, twoqw), 0.0f));
  }

  // Combine 4 segments (ssum is uniform within a segment).
  float acc = ssum * (1.0f / KNN);
  acc += __shfl_xor(acc, 16, 64);
  acc += __shfl_xor(acc, 32, 64);
  if (lane == 0) bsum[wv] = acc;
  __syncthreads();
  if (tid == 0)
    atomicAdd(out, (bsum[0] + bsum[1] + bsum[2] + bsum[3]) * (1.0f / (B * N)));
}

extern "C" void kernel_launch(void* const* d_in, const int* in_sizes, int n_in,
                              void* d_out, int out_size, void* d_ws, size_t ws_size,
                              hipStream_t stream) {
  const float* src = (const float*)d_in[0];
  const float* tgt = (const float*)d_in[1];
  const float* flow = (const float*)d_in[2];
  float* out = (float*)d_out;

  float4* pred_s = (float4*)d_ws;                        // 512 KB
  float4* tgt_s = pred_s + B * N;                        // 512 KB
  float4* gbox = tgt_s + B * N;                          // 128 KB
  float4* sbox = gbox + NCB * 2 * NGRP;                  // 16 KB
  int* starts = (int*)(sbox + NCB * 2 * NSUP);           // 131 KB

  prep_kernel<<<NCB, 1024, 0, stream>>>(src, tgt, flow, pred_s, tgt_s, starts,
                                        gbox, sbox, out);
  chamfer_kernel<<<(2 * B * N) / 16, 256, 0, stream>>>(pred_s, tgt_s, starts,
                                                       gbox, sbox, out);
}

// Round 8
// 207.168 us; speedup vs baseline: 1.3962x; 1.3962x over previous
//
#include <hip/hip_runtime.h>
#include <math.h>

constexpr int B = 4;
constexpr int N = 8192;
constexpr int KNN = 8;
constexpr int NCELL = 4096;              // 16^3 Morton cells
constexpr int GSIZE = 16;                // points per group
constexpr int NGRP = N / GSIZE;          // 512 groups per cloud-batch
constexpr int NSUP = 64;                 // supers: 8 groups (128 pts)
constexpr int NCB = 2 * B;               // cloud-batches (0-3 pred, 4-7 tgt)

// Insert tv into sorted ascending d[0..7]. Exact: d'[0]=min(d0,tv),
// d'[i]=med3(d[i-1],d[i],tv). 8 independent ops. INF insert is a no-op.
__device__ __forceinline__ void insert8(float (&d)[KNN], float tv) {
  float n0 = fminf(d[0], tv);
  float n1 = __builtin_amdgcn_fmed3f(d[0], d[1], tv);
  float n2 = __builtin_amdgcn_fmed3f(d[1], d[2], tv);
  float n3 = __builtin_amdgcn_fmed3f(d[2], d[3], tv);
  float n4 = __builtin_amdgcn_fmed3f(d[3], d[4], tv);
  float n5 = __builtin_amdgcn_fmed3f(d[4], d[5], tv);
  float n6 = __builtin_amdgcn_fmed3f(d[5], d[6], tv);
  float n7 = __builtin_amdgcn_fmed3f(d[6], d[7], tv);
  d[0] = n0; d[1] = n1; d[2] = n2; d[3] = n3;
  d[4] = n4; d[5] = n5; d[6] = n6; d[7] = n7;
}

__device__ __forceinline__ int morton3(int x, int y, int z) {
  int m = 0;
#pragma unroll
  for (int b = 0; b < 4; ++b)
    m |= (((x >> b) & 1) << (3 * b + 2)) | (((y >> b) & 1) << (3 * b + 1)) |
         (((z >> b) & 1) << (3 * b + 0));
  return m;
}

__device__ __forceinline__ int point_cell(float x, float y, float z) {
  int cx = (int)fminf(fmaxf((x + 4.0f) * 2.0f, 0.0f), 15.0f);
  int cy = (int)fminf(fmaxf((y + 4.0f) * 2.0f, 0.0f), 15.0f);
  int cz = (int)fminf(fmaxf((z + 4.0f) * 2.0f, 0.0f), 15.0f);
  return morton3(cx, cy, cz);
}

// One block per cloud-batch (8 blocks x 1024 threads). LDS histogram ->
// in-block scan (global starts) -> scatter (points in registers) ->
// group/super AABBs. Verified structure (absmax 0 since round 4).
__global__ __launch_bounds__(1024) void prep_kernel(
    const float* __restrict__ src, const float* __restrict__ tgt,
    const float* __restrict__ flow, float4* __restrict__ pred_s,
    float4* __restrict__ tgt_s, int* __restrict__ starts,
    float4* __restrict__ gbox, float4* __restrict__ sbox,
    float* __restrict__ out) {
  __shared__ int hist[NCELL];              // 16 KB: counts -> cursor
  __shared__ int wsum[16];
  __shared__ float4 gcache[2 * NGRP];      // 16 KB
  int tid = threadIdx.x, cb = blockIdx.x;
  int cloud = cb >> 2, batch = cb & 3;
  if (cb == 0 && tid == 0) out[0] = 0.0f;

  for (int i = tid; i < NCELL; i += 1024) hist[i] = 0;
  __syncthreads();

  const float* __restrict__ bp = (cloud == 0 ? src : tgt) + batch * N * 3;
  const float* __restrict__ bf = flow + batch * N * 3;
  float4 pt[8];
  int cell[8];
#pragma unroll
  for (int k = 0; k < 8; ++k) {
    int i = k * 1024 + tid;
    float x = bp[3 * i + 0], y = bp[3 * i + 1], z = bp[3 * i + 2];
    if (cloud == 0) { x += bf[3 * i + 0]; y += bf[3 * i + 1]; z += bf[3 * i + 2]; }
    pt[k] = make_float4(x, y, z, 0.5f * (x * x + y * y + z * z));
    cell[k] = point_cell(x, y, z);
    atomicAdd(&hist[cell[k]], 1);
  }
  __syncthreads();

  int b4 = tid * 4;
  int h0v = hist[b4 + 0], h1v = hist[b4 + 1];
  int h2v = hist[b4 + 2], h3v = hist[b4 + 3];
  int s = h0v + h1v + h2v + h3v;
  int lane = tid & 63, w = tid >> 6;
  int incl = s;
#pragma unroll
  for (int off = 1; off < 64; off <<= 1) {
    int u = __shfl_up(incl, off, 64);
    if (lane >= off) incl += u;
  }
  if (lane == 63) wsum[w] = incl;
  __syncthreads();
  if (tid < 16) {
    int v = wsum[tid], inc = v;
#pragma unroll
    for (int off = 1; off < 16; off <<= 1) {
      int u = __shfl_up(inc, off, 64);
      if (tid >= off) inc += u;
    }
    wsum[tid] = inc - v;
  }
  __syncthreads();
  int run = incl - s + wsum[w];
  int* __restrict__ stg = starts + cb * (NCELL + 1);
  stg[b4 + 0] = run; hist[b4 + 0] = run; run += h0v;
  stg[b4 + 1] = run; hist[b4 + 1] = run; run += h1v;
  stg[b4 + 2] = run; hist[b4 + 2] = run; run += h2v;
  stg[b4 + 3] = run; hist[b4 + 3] = run; run += h3v;
  if (tid == 0) stg[NCELL] = N;
  __syncthreads();

  float4* __restrict__ dst = (cloud == 0 ? pred_s : tgt_s) + batch * N;
#pragma unroll
  for (int k = 0; k < 8; ++k) {
    int pos = atomicAdd(&hist[cell[k]], 1);
    dst[pos] = pt[k];
  }
  __threadfence_block();
  __syncthreads();

  if (tid < NGRP) {
    const float4* __restrict__ sp = dst + tid * GSIZE;
    float lx = INFINITY, ly = INFINITY, lz = INFINITY;
    float hx = -INFINITY, hy = -INFINITY, hz = -INFINITY;
#pragma unroll
    for (int t = 0; t < GSIZE; ++t) {
      float4 p = sp[t];
      lx = fminf(lx, p.x); ly = fminf(ly, p.y); lz = fminf(lz, p.z);
      hx = fmaxf(hx, p.x); hy = fmaxf(hy, p.y); hz = fmaxf(hz, p.z);
    }
    float4 lo = make_float4(lx, ly, lz, 0.0f);
    float4 hi = make_float4(hx, hy, hz, 0.0f);
    gcache[2 * tid] = lo; gcache[2 * tid + 1] = hi;
    gbox[cb * 2 * NGRP + 2 * tid + 0] = lo;
    gbox[cb * 2 * NGRP + 2 * tid + 1] = hi;
  }
  __syncthreads();
  if (tid < NSUP) {
    float lx = INFINITY, ly = INFINITY, lz = INFINITY;
    float hx = -INFINITY, hy = -INFINITY, hz = -INFINITY;
#pragma unroll
    for (int t = 0; t < 8; ++t) {
      float4 lo = gcache[2 * (tid * 8 + t)], hi = gcache[2 * (tid * 8 + t) + 1];
      lx = fminf(lx, lo.x); ly = fminf(ly, lo.y); lz = fminf(lz, lo.z);
      hx = fmaxf(hx, hi.x); hy = fmaxf(hy, hi.y); hz = fmaxf(hz, hi.z);
    }
    sbox[cb * 2 * NSUP + 2 * tid + 0] = make_float4(lx, ly, lz, 0.0f);
    sbox[cb * 2 * NSUP + 2 * tid + 1] = make_float4(hx, hy, hz, 0.0f);
  }
}

// Wave = 16 consecutive sorted queries (qi = lane&15) x 4 point-slots
// (slot = lane>>4). Every candidate group of 16 points is processed DENSELY
// by the whole wave: round r, lane(slot,qi) takes point 4r+slot vs query qi
// (3.4 inst per query-candidate, all 64 lanes active, no shuffles). Pruning:
// seed = rank-matched super (128 pts); thr(qi) = max over slots of per-slot
// 2nd-smallest (8 distinct seed candidates <= it => >= seed-d8 >= final d8);
// supers then groups box-tested 4-per-round, verdicts OR-reduced over the 16
// queries via one ballot per round into wave-uniform bitmasks; drain iterates
// the masks with zero cross-lane ops. Skips are exact: boxmin <= true dist^2
// and thr >= final d8 (1e-5 margins cover fp). Slots see disjoint points, so
// the final 2-round shfl_xor merge (independent shuffles) is duplicate-free.
__global__ __launch_bounds__(256, 4) void chamfer_kernel(
    const float4* __restrict__ pred_s, const float4* __restrict__ tgt_s,
    const int* __restrict__ starts, const float4* __restrict__ gbox,
    const float4* __restrict__ sbox, float* __restrict__ out) {
  __shared__ float bsum[4];
  int tid = threadIdx.x;
  int lane = tid & 63;
  int wv = tid >> 6;
  int qi = lane & 15;
  int slot = lane >> 4;
  int wave_id = blockIdx.x * 4 + wv;       // 0..4095
  int base = wave_id * 16;                 // first query (global)
  int qcb = base >> 13;                    // uniform per wave
  int ccb = qcb ^ 4;                       // opposite cloud, same batch
  const float4* __restrict__ qarr = (qcb < 4 ? pred_s : tgt_s) + (qcb & 3) * N;
  const float4* __restrict__ parr = (ccb < 4 ? pred_s : tgt_s) + (ccb & 3) * N;
  const int* __restrict__ st = starts + ccb * (NCELL + 1);
  const float4* __restrict__ gb = gbox + ccb * (2 * NGRP);
  const float4* __restrict__ sb = sbox + ccb * (2 * NSUP);

  float4 q = qarr[(base & (N - 1)) + qi];
  float nqx = -q.x, nqy = -q.y, nqz = -q.z, twoqw = 2.0f * q.w;
  float d[KNN];
#pragma unroll
  for (int i = 0; i < KNN; ++i) d[i] = INFINITY;

  auto dist = [&](float4 p) {
    return __builtin_fmaf(nqx, p.x, __builtin_fmaf(nqy, p.y,
           __builtin_fmaf(nqz, p.z, p.w)));
  };
  auto process = [&](int g) {              // dense: 16 pts x 16 queries
    const float4* __restrict__ gp = parr + g * GSIZE;
#pragma unroll
    for (int r = 0; r < 4; ++r) {
      float4 p = gp[r * 4 + slot];         // 4 distinct addrs, L1 broadcast
      insert8(d, dist(p));
    }
  };
  auto boxmd = [&](const float4* __restrict__ bx) {
    float4 lo = bx[0], hi = bx[1];
    float ax = fmaxf(fmaxf(lo.x - q.x, q.x - hi.x), 0.0f);
    float ay = fmaxf(fmaxf(lo.y - q.y, q.y - hi.y), 0.0f);
    float az = fmaxf(fmaxf(lo.z - q.z, q.z - hi.z), 0.0f);
    return __builtin_fmaf(ax, ax, __builtin_fmaf(ay, ay, az * az));
  };

  // Seed: rank-matched super (anchor = middle query's cell rank).
  int ge = st[point_cell(q.x, q.y, q.z)];
  int geu = __shfl(ge, 8, 64);             // middle query, wave-uniform value
  int s0 = min(geu >> 7, NSUP - 1);
#pragma unroll 2
  for (int k = 0; k < 8; ++k) process(s0 * 8 + k);

  // thr(qi): per-slot 2nd-smallest, max over the 4 slots (>= seed d8).
  float m1 = fmaxf(d[1], __shfl_xor(d[1], 16, 64));
  m1 = fmaxf(m1, __shfl_xor(m1, 32, 64));
  float thr = __builtin_fmaf(2.0f, m1, twoqw) * 1.00001f + 1e-5f;

  // Super tests: 4 supers/round x 16 queries; one ballot OR-reduces the
  // 16-query verdicts; masks are wave-uniform (scalar ops, no shuffles).
  unsigned long long smask = 0;
#pragma unroll 4
  for (int t = 0; t < 16; ++t) {
    int s = t * 4 + slot;
    unsigned long long b = __ballot(boxmd(sb + 2 * s) < thr);
    unsigned m = ((b & 0xFFFFull) ? 1u : 0u) |
                 (((b >> 16) & 0xFFFFull) ? 2u : 0u) |
                 (((b >> 32) & 0xFFFFull) ? 4u : 0u) |
                 ((b >> 48) ? 8u : 0u);
    smask |= (unsigned long long)m << (t * 4);
  }
  smask &= ~(1ull << s0);                  // never re-process the seed super

  // Per passing super: test its 8 groups (2 rounds), drain passing groups.
  while (smask) {
    int s = (int)__builtin_ctzll(smask);
    smask &= smask - 1;
    unsigned gm = 0;
#pragma unroll
    for (int h = 0; h < 2; ++h) {
      int g = s * 8 + h * 4 + slot;
      unsigned long long b = __ballot(boxmd(gb + 2 * g) < thr);
      unsigned m = ((b & 0xFFFFull) ? 1u : 0u) |
                   (((b >> 16) & 0xFFFFull) ? 2u : 0u) |
                   (((b >> 32) & 0xFFFFull) ? 4u : 0u) |
                   ((b >> 48) ? 8u : 0u);
      gm |= m << (h * 4);
    }
    while (gm) {
      int j = __builtin_ctz(gm);
      gm &= gm - 1;
      process(s * 8 + j);
    }
  }

  // Merge the 4 disjoint slot lists per query (independent shuffles only).
#pragma unroll
  for (int m = 16; m <= 32; m <<= 1) {
    float od[KNN];
#pragma unroll
    for (int i = 0; i < KNN; ++i) od[i] = __shfl_xor(d[i], m, 64);
#pragma unroll
    for (int i = 0; i < KNN; ++i) insert8(d, od[i]);
  }

  // Loss: one value per query (slot 0), reduce wave -> block -> global.
  float val = 0.0f;
  if (slot == 0) {
    float s_ = 0.0f;
#pragma unroll
    for (int i = 0; i < KNN; ++i)
      s_ += sqrtf(fmaxf(__builtin_fmaf(2.0f, d[i], twoqw), 0.0f));
    val = s_ * (1.0f / KNN);
  }
  for (int off = 32; off; off >>= 1) val += __shfl_down(val, off, 64);
  if (lane == 0) bsum[wv] = val;
  __syncthreads();
  if (tid == 0)
    atomicAdd(out, (bsum[0] + bsum[1] + bsum[2] + bsum[3]) * (1.0f / (B * N)));
}

extern "C" void kernel_launch(void* const* d_in, const int* in_sizes, int n_in,
                              void* d_out, int out_size, void* d_ws, size_t ws_size,
                              hipStream_t stream) {
  const float* src = (const float*)d_in[0];
  const float* tgt = (const float*)d_in[1];
  const float* flow = (const float*)d_in[2];
  float* out = (float*)d_out;

  float4* pred_s = (float4*)d_ws;                        // 512 KB
  float4* tgt_s = pred_s + B * N;                        // 512 KB
  float4* gbox = tgt_s + B * N;                          // 128 KB
  float4* sbox = gbox + NCB * 2 * NGRP;                  // 16 KB
  int* starts = (int*)(sbox + NCB * 2 * NSUP);           // 131 KB

  prep_kernel<<<NCB, 1024, 0, stream>>>(src, tgt, flow, pred_s, tgt_s, starts,
                                        gbox, sbox, out);
  chamfer_kernel<<<(2 * B * N) / 64, 256, 0, stream>>>(pred_s, tgt_s, starts,
                                                       gbox, sbox, out);
}

// Round 9
// 175.632 us; speedup vs baseline: 1.6469x; 1.1796x over previous
//
#include <hip/hip_runtime.h>
#include <math.h>

constexpr int B = 4;
constexpr int N = 8192;
constexpr int KNN = 8;
constexpr int NCELL = 4096;              // 16^3 Morton cells
constexpr int GSIZE = 16;                // points per group
constexpr int NGRP = N / GSIZE;          // 512 groups per cloud-batch
constexpr int NSUP = 64;                 // supers: 8 groups (128 pts)
constexpr int NCB = 2 * B;               // cloud-batches (0-3 pred, 4-7 tgt)

// Insert tv into sorted ascending d[0..7]. Exact: d'[0]=min(d0,tv),
// d'[i]=med3(d[i-1],d[i],tv). 8 independent ops. INF insert is a no-op.
__device__ __forceinline__ void insert8(float (&d)[KNN], float tv) {
  float n0 = fminf(d[0], tv);
  float n1 = __builtin_amdgcn_fmed3f(d[0], d[1], tv);
  float n2 = __builtin_amdgcn_fmed3f(d[1], d[2], tv);
  float n3 = __builtin_amdgcn_fmed3f(d[2], d[3], tv);
  float n4 = __builtin_amdgcn_fmed3f(d[3], d[4], tv);
  float n5 = __builtin_amdgcn_fmed3f(d[4], d[5], tv);
  float n6 = __builtin_amdgcn_fmed3f(d[5], d[6], tv);
  float n7 = __builtin_amdgcn_fmed3f(d[6], d[7], tv);
  d[0] = n0; d[1] = n1; d[2] = n2; d[3] = n3;
  d[4] = n4; d[5] = n5; d[6] = n6; d[7] = n7;
}

__device__ __forceinline__ int morton3(int x, int y, int z) {
  int m = 0;
#pragma unroll
  for (int b = 0; b < 4; ++b)
    m |= (((x >> b) & 1) << (3 * b + 2)) | (((y >> b) & 1) << (3 * b + 1)) |
         (((z >> b) & 1) << (3 * b + 0));
  return m;
}

__device__ __forceinline__ int point_cell(float x, float y, float z) {
  int cx = (int)fminf(fmaxf((x + 4.0f) * 2.0f, 0.0f), 15.0f);
  int cy = (int)fminf(fmaxf((y + 4.0f) * 2.0f, 0.0f), 15.0f);
  int cz = (int)fminf(fmaxf((z + 4.0f) * 2.0f, 0.0f), 15.0f);
  return morton3(cx, cy, cz);
}

// Collapse each byte of a 64-bit ballot to one bit (bit k = byte k != 0).
// Masked OR-fold (leak-free) + gather-multiply; pure SALU.
__device__ __forceinline__ unsigned bytes_to_bits(unsigned long long b) {
  b |= b >> 4; b &= 0x0F0F0F0F0F0F0F0Full;
  b |= b >> 2; b &= 0x0303030303030303ull;
  b |= b >> 1; b &= 0x0101010101010101ull;
  return (unsigned)((b * 0x0102040810204080ull) >> 56) & 0xFF;
}

// One block per cloud-batch (8 blocks x 1024 threads). LDS histogram ->
// in-block scan (global starts) -> scatter (points in registers) ->
// group/super AABBs. Verified structure (absmax 0 since round 4).
__global__ __launch_bounds__(1024) void prep_kernel(
    const float* __restrict__ src, const float* __restrict__ tgt,
    const float* __restrict__ flow, float4* __restrict__ pred_s,
    float4* __restrict__ tgt_s, int* __restrict__ starts,
    float4* __restrict__ gbox, float4* __restrict__ sbox,
    float* __restrict__ out) {
  __shared__ int hist[NCELL];              // 16 KB: counts -> cursor
  __shared__ int wsum[16];
  __shared__ float4 gcache[2 * NGRP];      // 16 KB
  int tid = threadIdx.x, cb = blockIdx.x;
  int cloud = cb >> 2, batch = cb & 3;
  if (cb == 0 && tid == 0) out[0] = 0.0f;

  for (int i = tid; i < NCELL; i += 1024) hist[i] = 0;
  __syncthreads();

  const float* __restrict__ bp = (cloud == 0 ? src : tgt) + batch * N * 3;
  const float* __restrict__ bf = flow + batch * N * 3;
  float4 pt[8];
  int cell[8];
#pragma unroll
  for (int k = 0; k < 8; ++k) {
    int i = k * 1024 + tid;
    float x = bp[3 * i + 0], y = bp[3 * i + 1], z = bp[3 * i + 2];
    if (cloud == 0) { x += bf[3 * i + 0]; y += bf[3 * i + 1]; z += bf[3 * i + 2]; }
    pt[k] = make_float4(x, y, z, 0.5f * (x * x + y * y + z * z));
    cell[k] = point_cell(x, y, z);
    atomicAdd(&hist[cell[k]], 1);
  }
  __syncthreads();

  int b4 = tid * 4;
  int h0v = hist[b4 + 0], h1v = hist[b4 + 1];
  int h2v = hist[b4 + 2], h3v = hist[b4 + 3];
  int s = h0v + h1v + h2v + h3v;
  int lane = tid & 63, w = tid >> 6;
  int incl = s;
#pragma unroll
  for (int off = 1; off < 64; off <<= 1) {
    int u = __shfl_up(incl, off, 64);
    if (lane >= off) incl += u;
  }
  if (lane == 63) wsum[w] = incl;
  __syncthreads();
  if (tid < 16) {
    int v = wsum[tid], inc = v;
#pragma unroll
    for (int off = 1; off < 16; off <<= 1) {
      int u = __shfl_up(inc, off, 64);
      if (tid >= off) inc += u;
    }
    wsum[tid] = inc - v;
  }
  __syncthreads();
  int run = incl - s + wsum[w];
  int* __restrict__ stg = starts + cb * (NCELL + 1);
  stg[b4 + 0] = run; hist[b4 + 0] = run; run += h0v;
  stg[b4 + 1] = run; hist[b4 + 1] = run; run += h1v;
  stg[b4 + 2] = run; hist[b4 + 2] = run; run += h2v;
  stg[b4 + 3] = run; hist[b4 + 3] = run; run += h3v;
  if (tid == 0) stg[NCELL] = N;
  __syncthreads();

  float4* __restrict__ dst = (cloud == 0 ? pred_s : tgt_s) + batch * N;
#pragma unroll
  for (int k = 0; k < 8; ++k) {
    int pos = atomicAdd(&hist[cell[k]], 1);
    dst[pos] = pt[k];
  }
  __threadfence_block();
  __syncthreads();

  if (tid < NGRP) {
    const float4* __restrict__ sp = dst + tid * GSIZE;
    float lx = INFINITY, ly = INFINITY, lz = INFINITY;
    float hx = -INFINITY, hy = -INFINITY, hz = -INFINITY;
#pragma unroll
    for (int t = 0; t < GSIZE; ++t) {
      float4 p = sp[t];
      lx = fminf(lx, p.x); ly = fminf(ly, p.y); lz = fminf(lz, p.z);
      hx = fmaxf(hx, p.x); hy = fmaxf(hy, p.y); hz = fmaxf(hz, p.z);
    }
    float4 lo = make_float4(lx, ly, lz, 0.0f);
    float4 hi = make_float4(hx, hy, hz, 0.0f);
    gcache[2 * tid] = lo; gcache[2 * tid + 1] = hi;
    gbox[cb * 2 * NGRP + 2 * tid + 0] = lo;
    gbox[cb * 2 * NGRP + 2 * tid + 1] = hi;
  }
  __syncthreads();
  if (tid < NSUP) {
    float lx = INFINITY, ly = INFINITY, lz = INFINITY;
    float hx = -INFINITY, hy = -INFINITY, hz = -INFINITY;
#pragma unroll
    for (int t = 0; t < 8; ++t) {
      float4 lo = gcache[2 * (tid * 8 + t)], hi = gcache[2 * (tid * 8 + t) + 1];
      lx = fminf(lx, lo.x); ly = fminf(ly, lo.y); lz = fminf(lz, lo.z);
      hx = fmaxf(hx, hi.x); hy = fmaxf(hy, hi.y); hz = fmaxf(hz, hi.z);
    }
    sbox[cb * 2 * NSUP + 2 * tid + 0] = make_float4(lx, ly, lz, 0.0f);
    sbox[cb * 2 * NSUP + 2 * tid + 1] = make_float4(hx, hy, hz, 0.0f);
  }
}

// Wave = 8 consecutive sorted queries (qi = lane&7) x 8 point-slots
// (slot = lane>>3). Dense processing: group of 16 pts handled in 2 rounds,
// lane(slot,qi) takes point r*8+slot vs query qi -- 1.5 wave-inst per
// query-candidate, all lanes always active, zero shuffles in loops.
// Threshold: EXACT seed d8 -- after seeding the rank-matched super (128 pts),
// a temp copy of the slot lists is fully merged (3 shfl_xor rounds); temp[7]
// is the true 8th-smallest over all 128 seeds; slot lists stay disjoint.
// thr(qi) >= final d8(qi), fixed; boxmin <= true dist^2 => skips exact
// (1e-5 margins cover fp rounding). Boxes are LDS-staged per block; ballots
// OR-reduce 8-query verdicts into wave-uniform SGPR masks (SALU only).
// Slots see disjoint point indices, so the final merge is duplicate-free.
__global__ __launch_bounds__(256, 8) void chamfer_kernel(
    const float4* __restrict__ pred_s, const float4* __restrict__ tgt_s,
    const int* __restrict__ starts, const float4* __restrict__ gbox,
    const float4* __restrict__ sbox, float* __restrict__ out) {
  __shared__ float4 sB[2 * NSUP];          // 2 KB super boxes
  __shared__ float4 gB[2 * NGRP];          // 16 KB group boxes
  __shared__ float bsum[4];
  int tid = threadIdx.x;
  int lane = tid & 63;
  int wv = tid >> 6;
  int qi = lane & 7;
  int slot = lane >> 3;
  int base = blockIdx.x * 32;              // 32 queries per block, same cb
  int qcb = base >> 13;
  int ccb = qcb ^ 4;                       // opposite cloud, same batch
  const float4* __restrict__ qarr = (qcb < 4 ? pred_s : tgt_s) + (qcb & 3) * N;
  const float4* __restrict__ parr = (ccb < 4 ? pred_s : tgt_s) + (ccb & 3) * N;
  const int* __restrict__ st = starts + ccb * (NCELL + 1);
  const float4* __restrict__ gbg = gbox + ccb * (2 * NGRP);
  const float4* __restrict__ sbg = sbox + ccb * (2 * NSUP);

  // Stage this candidate cloud's boxes into LDS (coalesced, once per block).
  for (int i = tid; i < 2 * NSUP; i += 256) sB[i] = sbg[i];
  for (int i = tid; i < 2 * NGRP; i += 256) gB[i] = gbg[i];
  __syncthreads();

  float4 q = qarr[(base & (N - 1)) + wv * 8 + qi];
  float nqx = -q.x, nqy = -q.y, nqz = -q.z, twoqw = 2.0f * q.w;
  float d[KNN];
#pragma unroll
  for (int i = 0; i < KNN; ++i) d[i] = INFINITY;

  auto dist = [&](float4 p) {
    return __builtin_fmaf(nqx, p.x, __builtin_fmaf(nqy, p.y,
           __builtin_fmaf(nqz, p.z, p.w)));
  };
  auto process = [&](int g) {              // 16 pts x 8 queries, dense
    const float4* __restrict__ gp = parr + g * GSIZE;
#pragma unroll
    for (int r = 0; r < 2; ++r) insert8(d, dist(gp[r * 8 + slot]));
  };
  auto boxmd = [&](const float4* bx) {     // LDS box
    float4 lo = bx[0], hi = bx[1];
    float ax = fmaxf(fmaxf(lo.x - q.x, q.x - hi.x), 0.0f);
    float ay = fmaxf(fmaxf(lo.y - q.y, q.y - hi.y), 0.0f);
    float az = fmaxf(fmaxf(lo.z - q.z, q.z - hi.z), 0.0f);
    return __builtin_fmaf(ax, ax, __builtin_fmaf(ay, ay, az * az));
  };

  // Seed: rank-matched super (anchor = middle query's cell rank).
  int ge = st[point_cell(q.x, q.y, q.z)];
  int geu = __shfl(ge, wv * 0 + 4, 64);    // lane 4 of the wave (qi=4, slot=0)
  int s0 = min(geu >> 7, NSUP - 1);
#pragma unroll
  for (int k = 0; k < 8; ++k) process(s0 * 8 + k);

  // Exact seed threshold: merge a TEMP copy across the 8 slots.
  float md[KNN];
#pragma unroll
  for (int i = 0; i < KNN; ++i) md[i] = d[i];
#pragma unroll
  for (int m = 8; m <= 32; m <<= 1) {
    float od[KNN];
#pragma unroll
    for (int i = 0; i < KNN; ++i) od[i] = __shfl_xor(md[i], m, 64);
#pragma unroll
    for (int i = 0; i < KNN; ++i) insert8(md, od[i]);
  }
  float thr = __builtin_fmaf(2.0f, md[KNN - 1], twoqw) * 1.00001f + 1e-5f;

  // Super tests: 8 rounds; round t tests supers t*8+k (lane tests k=slot for
  // its query); one ballot per round -> byte k = verdicts of super t*8+k.
  unsigned long long smask = 0;
#pragma unroll
  for (int t = 0; t < 8; ++t) {
    unsigned long long bl = __ballot(boxmd(&sB[2 * (t * 8 + slot)]) < thr);
    smask |= (unsigned long long)bytes_to_bits(bl) << (t * 8);
  }
  smask &= ~(1ull << s0);                  // seed super already processed

  // Per passing super: test its 8 groups in ONE round, drain passing groups.
  while (smask) {
    int s = (int)__builtin_ctzll(smask);
    smask &= smask - 1;
    unsigned gm = bytes_to_bits(__ballot(boxmd(&gB[2 * (s * 8 + slot)]) < thr));
    while (gm) {
      int j = __builtin_ctz(gm);
      gm &= gm - 1;
      process(s * 8 + j);
    }
  }

  // Final merge of the 8 disjoint slot lists (in place).
#pragma unroll
  for (int m = 8; m <= 32; m <<= 1) {
    float od[KNN];
#pragma unroll
    for (int i = 0; i < KNN; ++i) od[i] = __shfl_xor(d[i], m, 64);
#pragma unroll
    for (int i = 0; i < KNN; ++i) insert8(d, od[i]);
  }

  // Loss: slot 0 lanes (0..7) hold the 8 queries' merged lists.
  float val = 0.0f;
  if (slot == 0) {
    float s_ = 0.0f;
#pragma unroll
    for (int i = 0; i < KNN; ++i)
      s_ += sqrtf(fmaxf(__builtin_fmaf(2.0f, d[i], twoqw), 0.0f));
    val = s_ * (1.0f / KNN);
  }
  val += __shfl_down(val, 4, 64);
  val += __shfl_down(val, 2, 64);
  val += __shfl_down(val, 1, 64);
  if (lane == 0) bsum[wv] = val;
  __syncthreads();
  if (tid == 0)
    atomicAdd(out, (bsum[0] + bsum[1] + bsum[2] + bsum[3]) * (1.0f / (B * N)));
}

extern "C" void kernel_launch(void* const* d_in, const int* in_sizes, int n_in,
                              void* d_out, int out_size, void* d_ws, size_t ws_size,
                              hipStream_t stream) {
  const float* src = (const float*)d_in[0];
  const float* tgt = (const float*)d_in[1];
  const float* flow = (const float*)d_in[2];
  float* out = (float*)d_out;

  float4* pred_s = (float4*)d_ws;                        // 512 KB
  float4* tgt_s = pred_s + B * N;                        // 512 KB
  float4* gbox = tgt_s + B * N;                          // 128 KB
  float4* sbox = gbox + NCB * 2 * NGRP;                  // 16 KB
  int* starts = (int*)(sbox + NCB * 2 * NSUP);           // 131 KB

  prep_kernel<<<NCB, 1024, 0, stream>>>(src, tgt, flow, pred_s, tgt_s, starts,
                                        gbox, sbox, out);
  chamfer_kernel<<<(2 * B * N) / 32, 256, 0, stream>>>(pred_s, tgt_s, starts,
                                                       gbox, sbox, out);
}